// Round 15
// baseline (4039.554 us; speedup 1.0000x reference)
//
#include <hip/hip_runtime.h>
#include <stdint.h>
#include <string.h>

#define NREAL 1793
#define NPAD  1824          // K padded to 57*32
#define NROWP 1808          // rows padded to 113*16
#define WSTR  1832          // LDS row stride (halves)
#define NBLK  113
#define NGRP  2
#define TSTEPS 300
#define BATCH 128
#define XS_OFF 68851200     // 128*300*1793
#define OUT_OFF 137702400   // 2*128*300*1793
#define LOFF (16 * WSTR)    // LDS offset of lo-plane
#define LOSCALE 4096.0f
#define LOINV  2.44140625e-4f

// sync area: one arrival slot per block, each on its own 128B line
#define ASLOT(g,i)    (((g) * 128 + (i)) * 32)

typedef _Float16 half_t;
typedef __attribute__((ext_vector_type(8))) _Float16 half8;
typedef __attribute__((ext_vector_type(4))) float f32x4;
typedef __attribute__((ext_vector_type(4))) unsigned int uint4v;

__device__ __forceinline__ float clipw(float w) {
  return fminf(fmaxf(w, 1e-10f), 1.0f);
}

// write-through-to-LLC 4B store (bypasses L1/L2 -> agent-visible)
__device__ __forceinline__ void store_u32_llc(unsigned int* p, unsigned int v) {
  asm volatile("global_store_dword %0, %1, off sc0 sc1"
               :: "v"((unsigned long long)(uintptr_t)p), "v"(v)
               : "memory");
}

__device__ __forceinline__ float unpack_h(uint32_t p) {
  unsigned short uh = (unsigned short)(p & 0xffffu);
  unsigned short ul = (unsigned short)(p >> 16);
  half_t hh = *(half_t*)&uh;
  half_t hl = *(half_t*)&ul;
  return (float)hh + LOINV * (float)hl;
}

// tile-region id: 0 d1lo, 1 d1hi, 2 d2, 3 stn, 4 thal, 5 alm, 6 iti
__device__ __forceinline__ int rid_of(int s) {
  return (s < 8) ? 0 : (s < 16) ? 1 : (s < 32) ? 2 : (s < 48) ? 3
       : (s < 80) ? 4 : (s < 112) ? 5 : 6;
}

// masked dual-min poll over the 113 arrival slots (wave-wide)
__device__ __forceinline__ void poll_wait(unsigned int* cnt, int g, int lane,
                                          bool in0, bool in1, bool cn0, bool cn1,
                                          unsigned tin, unsigned tcn)
{
  const int s0 = lane, s1 = lane + 64;
  for (;;) {
    unsigned a0 = __hip_atomic_load(&cnt[ASLOT(g, s0)], __ATOMIC_RELAXED,
                                    __HIP_MEMORY_SCOPE_AGENT);
    unsigned a1 = 0xFFFFFFFFu;
    if (in1 || cn1)
      a1 = __hip_atomic_load(&cnt[ASLOT(g, s1)], __ATOMIC_RELAXED,
                             __HIP_MEMORY_SCOPE_AGENT);
    unsigned vin = in0 ? a0 : 0xFFFFFFFFu;
    if (in1 && a1 < vin) vin = a1;
    unsigned vcn = cn0 ? a0 : 0xFFFFFFFFu;
    if (cn1 && a1 < vcn) vcn = a1;
    #pragma unroll
    for (int o = 32; o; o >>= 1) {
      unsigned x = __shfl_xor(vin, o); if (x < vin) vin = x;
      unsigned y = __shfl_xor(vcn, o); if (y < vcn) vcn = y;
    }
    if (vin >= tin && vcn >= tcn) break;
    __builtin_amdgcn_s_sleep(1);
  }
}

// burst-load all A fragments for this region's chunk segments, then unpack+MFMA
template<int LO0, int N0, int LO1, int N1, int LO2, int N2>
__device__ __forceinline__ void seg_mfma(const uint32_t* __restrict__ ap,
                                         const half_t* __restrict__ Wl, int wl_b,
                                         f32x4& acc0, f32x4& acc1, f32x4& acc2)
{
  constexpr int NC = N0 + N1 + N2;
  if (NC == 0) return;
  uint4v q0[NC ? NC : 1], q1[NC ? NC : 1];
  #pragma unroll
  for (int i = 0; i < NC; ++i) {
    const int kc = (i < N0) ? (LO0 + i)
                 : (i < N0 + N1) ? (LO1 + i - N0)
                 : (LO2 + i - N0 - N1);
    q0[i] = *(const uint4v*)(ap + kc * 32);
    q1[i] = *(const uint4v*)(ap + kc * 32 + 4);
  }
  #pragma unroll
  for (int i = 0; i < NC; ++i) {
    const int kc = (i < N0) ? (LO0 + i)
                 : (i < N0 + N1) ? (LO1 + i - N0)
                 : (LO2 + i - N0 - N1);
    uint4v uh, ul;
    uh.x = __builtin_amdgcn_perm(q0[i].y, q0[i].x, 0x05040100u);
    uh.y = __builtin_amdgcn_perm(q0[i].w, q0[i].z, 0x05040100u);
    uh.z = __builtin_amdgcn_perm(q1[i].y, q1[i].x, 0x05040100u);
    uh.w = __builtin_amdgcn_perm(q1[i].w, q1[i].z, 0x05040100u);
    ul.x = __builtin_amdgcn_perm(q0[i].y, q0[i].x, 0x07060302u);
    ul.y = __builtin_amdgcn_perm(q0[i].w, q0[i].z, 0x07060302u);
    ul.z = __builtin_amdgcn_perm(q1[i].y, q1[i].x, 0x07060302u);
    ul.w = __builtin_amdgcn_perm(q1[i].w, q1[i].z, 0x07060302u);
    union { uint4v u; half8 h; } ch, cl;
    ch.u = uh; cl.u = ul;
    half8 bvh = *(const half8*)&Wl[wl_b + kc * 32];
    half8 bvl = *(const half8*)&Wl[LOFF + wl_b + kc * 32];
    acc0 = __builtin_amdgcn_mfma_f32_16x16x32_f16(ch.h, bvh, acc0, 0, 0, 0);
    acc1 = __builtin_amdgcn_mfma_f32_16x16x32_f16(ch.h, bvl, acc1, 0, 0, 0);
    acc2 = __builtin_amdgcn_mfma_f32_16x16x32_f16(cl.h, bvh, acc2, 0, 0, 0);
  }
}

// ---------------- W build (two fp16 planes: hi, lo*4096) ----------------
__global__ __launch_bounds__(256)
void build_w(const float* __restrict__ d12d1, const float* __restrict__ d12d2,
             const float* __restrict__ d22d1, const float* __restrict__ d22d2,
             const float* __restrict__ d22stn, const float* __restrict__ d12thal,
             const float* __restrict__ stn2thal, const float* __restrict__ thal2alm,
             const float* __restrict__ alm2alm, const float* __restrict__ thal2d1,
             const float* __restrict__ thal2d2, const float* __restrict__ alm2d1,
             const float* __restrict__ alm2d2, const float* __restrict__ inpw1,
             const float* __restrict__ inpw2, const unsigned int* __restrict__ mbits,
             half_t* __restrict__ W)
{
  int idx = blockIdx.x * 256 + threadIdx.x;
  if (idx >= NROWP * NPAD) return;
  int i = idx / NPAD, j = idx - (idx / NPAD) * NPAD;
  float v = 0.f;
  if (i < NREAL && j < NREAL) {
    if (i < 256) {
      if (j < 512) {
        int jj = j & 255;
        unsigned bit = (mbits[(i << 3) + (jj >> 5)] >> (jj & 31)) & 1u;
        float wv = (j < 256) ? d12d1[(i << 8) + jj] : d22d1[(i << 8) + jj];
        v = bit ? -clipw(wv) : 0.f;
      } else if (j < 768) {
      } else if (j < 1280) {
        if (i < 128) v = clipw(thal2d1[(i << 9) + (j - 768)]);
      } else if (j < 1792) {
        int jj = j - 1280;
        if (i >= 128 && jj < 359) v = clipw(alm2d1[(i << 9) + jj]);
      } else {
        if (i < 128) v = clipw(inpw1[i]);
      }
    } else if (i < 512) {
      int ii = i - 256;
      if (j < 512) {
        int jj = j & 255;
        unsigned bit = (mbits[(ii << 3) + (jj >> 5)] >> (jj & 31)) & 1u;
        float wv = (j < 256) ? d12d2[(ii << 8) + jj] : d22d2[(ii << 8) + jj];
        v = bit ? -clipw(wv) : 0.f;
      } else if (j < 768) {
      } else if (j < 1280) {
        v = clipw(thal2d2[(ii << 9) + (j - 768)]);
      } else if (j < 1792) {
        int jj = j - 1280;
        if (jj < 359) v = clipw(alm2d2[(ii << 9) + jj]);
      } else {
        v = clipw(inpw2[ii]);
      }
    } else if (i < 768) {
      int ii = i - 512;
      if (j >= 256 && j < 512) v = clipw(d22stn[(ii << 8) + (j - 256)]);
    } else if (i < 1280) {
      int ii = i - 768;
      if (j < 256) v = clipw(d12thal[(ii << 8) + j]);
      else if (j >= 512 && j < 768) v = -clipw(stn2thal[(ii << 8) + (j - 512)]);
    } else if (i < 1792) {
      int ii = i - 1280;
      if (j >= 768 && j < 1280) v = clipw(thal2alm[(ii << 9) + (j - 768)]);
      else if (j >= 1280) {
        int jj = j - 1280;
        v = clipw(alm2alm[(ii << 9) + jj]) * ((jj < 359) ? 1.f : -1.f);
      }
    }
  }
  half_t vh = (half_t)v;
  half_t vl = (half_t)((v - (float)vh) * LOSCALE);
  W[idx] = vh;                                  // hi plane
  W[(size_t)NROWP * NPAD + idx] = vl;           // lo plane (scaled)
}

// ---------------- h0 init (packed dword per unit; ring buffer 0) ----------------
__global__ __launch_bounds__(256)
void init_h(const float* __restrict__ hn, uint32_t* __restrict__ hbuf)
{
  const size_t P4 = (size_t)BATCH * NPAD;
  int idx = blockIdx.x * 256 + threadIdx.x;
  if (idx >= BATCH * NPAD) return;
  int b = idx / NPAD, k = idx - b * NPAD;
  float v = (k < NREAL) ? hn[b * NREAL + k] : 0.f;
  half_t vh = (half_t)v;
  half_t vl = (half_t)((v - (float)vh) * LOSCALE);
  uint32_t hp = (uint32_t)(*(unsigned short*)&vh) |
                ((uint32_t)(*(unsigned short*)&vl) << 16);
  hbuf[idx]      = hp;   // ring buf 0 = h@0
  hbuf[P4 + idx] = 0u;   // ring buf 1 cleared (2,3 are W-zero-protected)
}

// ---------------- main cooperative RNN kernel (226 blocks x 4 waves) ----------------
__global__ __launch_bounds__(256, 1)
void rnn_step_all(const half_t* __restrict__ Wg, uint32_t* __restrict__ hbuf,
                  unsigned int* __restrict__ cnt,
                  const float* __restrict__ inp, const float* __restrict__ cue,
                  const float* __restrict__ inhib, const float* __restrict__ noise,
                  const float* __restrict__ xn, const float* __restrict__ outw,
                  float* __restrict__ dout)
{
  __shared__ __align__(16) half_t Wl[2 * 16 * WSTR];   // 117 KB: hi + lo planes
  const int tid = threadIdx.x;
  const int bid = blockIdx.x;
  const int g  = bid / NBLK;
  const int nb = bid - g * NBLK;
  const int r0 = nb * 16;
  const int bg = g * 64;
  const size_t P4 = (size_t)BATCH * NPAD;

  const int lane = tid & 63;
  const int w    = tid >> 6;      // wave = M-tile (16 batch rows)
  const int n_i  = lane & 15;     // output unit within tile
  const int kq   = lane >> 4;     // k-subgroup
  const int row  = r0 + n_i;      // global unit index
  const bool valid = row < NREAL;
  const int b0 = bg + 16 * w + kq * 4;   // batch base for the 4 acc regs
  const int bA = bg + 16 * w + n_i;      // batch row this lane loads for A-frag
  const int wl_b = n_i * WSTR + kq * 8;
  const bool is_outblk = (r0 == 512);    // one near-idle stn block per group
  const bool poll_wave = (tid < 64);

  // ---- dataflow masks ----
  const int myrid = rid_of(nb);
  const unsigned INB =
      (myrid == 0) ? 87u : (myrid == 1) ? 39u : (myrid == 2) ? 119u :
      (myrid == 3) ? ((nb == 32) ? 36u : 4u) :
      (myrid == 4) ? 11u : (myrid == 5) ? 48u : 0u;
  const unsigned CONSB =
      (myrid <= 1) ? 23u : (myrid == 2) ? 15u : (myrid == 3) ? 16u :
      (myrid == 4) ? 37u : (myrid == 5) ? 46u : 5u;
  const int s1 = lane + 64;
  const int rid0 = rid_of(lane);
  const int rid1 = (s1 < NBLK) ? rid_of(s1) : 6;
  const bool in0 = (lane != nb) && ((INB >> rid0) & 1);
  const bool in1 = (s1 < NBLK) && (s1 != nb) && ((INB >> rid1) & 1);
  const bool cn0 = ((CONSB >> rid0) & 1);
  const bool cn1 = (s1 < NBLK) && ((CONSB >> rid1) & 1);

  // preload t=0 streams (overlaps W staging)
  float inh[4], noi[4];
  #pragma unroll
  for (int r = 0; r < 4; ++r) {
    inh[r] = 0.f; noi[r] = 0.f;
    if (valid) {
      int ei = ((b0 + r) * TSTEPS) * NREAL + row;
      inh[r] = __builtin_nontemporal_load(&inhib[ei]);
      noi[r] = __builtin_nontemporal_load(&noise[ei]);
    }
  }

  // stage this block's 16 W rows, both planes, into LDS (reused for 300 steps)
  for (int idx = tid; idx < 2 * 16 * (NPAD / 8); idx += 256) {
    int p   = idx / (16 * (NPAD / 8));
    int rem = idx - p * 16 * (NPAD / 8);
    int rr  = rem / (NPAD / 8);
    int cc  = (rem - rr * (NPAD / 8)) * 8;
    *(uint4v*)&Wl[p * LOFF + rr * WSTR + cc] =
        *(const uint4v*)&Wg[(size_t)p * NROWP * NPAD + (size_t)(r0 + rr) * NPAD + cc];
  }
  __syncthreads();

  float xr[4];
  #pragma unroll
  for (int r = 0; r < 4; ++r)
    xr[r] = valid ? xn[(size_t)(b0 + r) * NREAL + row] : 0.f;

  const float tonic = (valid && row < 1792) ? 0.1f : 0.f;
  const bool is_iti = (row == 1792);

  // out-compute lane mapping (used only by out blocks)
  const int ob    = bg + 16 * w + (lane >> 2);   // batch this lane helps with
  const int opart = lane & 3;
  const int ou0   = opart * 90;
  const int onu   = (opart == 3) ? 89 : 90;

  #pragma unroll 1
  for (int t = 0; t < TSTEPS; ++t) {
    // ---- dataflow wait: inputs@t available, consumers consumed h@t-3 ----
    if (t >= 1) {
      if (poll_wave) {
        poll_wait(cnt, g, lane, in0, in1, cn0, cn1,
                  (unsigned)t, (t >= 2) ? (unsigned)(t - 2) : 0u);
        __builtin_amdgcn_fence(__ATOMIC_ACQUIRE, "agent");   // L1+L2 inv
        asm volatile("s_waitcnt vmcnt(0)" ::: "memory");
      }
      __builtin_amdgcn_s_barrier();
      asm volatile("" ::: "memory");
    }

    const uint32_t* hr = hbuf + (size_t)(t & 3) * P4;        // h@t (ring)
    uint32_t*       hw = hbuf + (size_t)((t + 1) & 3) * P4;  // h@t+1

    float itv[4];
    #pragma unroll
    for (int r = 0; r < 4; ++r) {
      int bt = (b0 + r) * TSTEPS + t;
      itv[r] = is_iti ? (inp[bt] + cue[bt]) : 0.f;
    }

    const uint32_t* ap = hr + (size_t)bA * NPAD + kq * 8;
    f32x4 acc0 = {0.f, 0.f, 0.f, 0.f};
    f32x4 acc1 = {0.f, 0.f, 0.f, 0.f};
    f32x4 acc2 = {0.f, 0.f, 0.f, 0.f};

    if      (r0 < 128)  seg_mfma<0, 16, 24, 16, 56, 1>(ap, Wl, wl_b, acc0, acc1, acc2);
    else if (r0 < 256)  seg_mfma<0, 16, 40, 12,  0, 0>(ap, Wl, wl_b, acc0, acc1, acc2);
    else if (r0 < 512)  seg_mfma<0, 16, 24, 28, 56, 1>(ap, Wl, wl_b, acc0, acc1, acc2);
    else if (r0 < 768)  seg_mfma<8,  8,  0,  0,  0, 0>(ap, Wl, wl_b, acc0, acc1, acc2);
    else if (r0 < 1280) seg_mfma<0,  8, 16,  8,  0, 0>(ap, Wl, wl_b, acc0, acc1, acc2);
    else if (r0 < 1792) seg_mfma<24, 32, 0,  0,  0, 0>(ap, Wl, wl_b, acc0, acc1, acc2);
    // r0 == 1792: zero W rows, acc stays 0

    // ---- epilogue: h stores FIRST (publish-critical), dout stores deferred ----
    float hvs[4], xvs[4];
    #pragma unroll
    for (int r = 0; r < 4; ++r) {
      float drive = acc0[r] + LOINV * (acc1[r] + acc2[r])
                    + tonic + inh[r] + 0.01f * noi[r] + itv[r];
      float xv = xr[r] + 0.1f * (drive - xr[r]);     // matches ref: x + dt*(-x+drive)
      float hv = fmaxf(xv, 0.f);
      xr[r] = xv; hvs[r] = hv; xvs[r] = xv;
      half_t hh = (half_t)hv;
      half_t hl = (half_t)((hv - (float)hh) * LOSCALE);
      uint32_t hp = (uint32_t)(*(unsigned short*)&hh) |
                    ((uint32_t)(*(unsigned short*)&hl) << 16);
      store_u32_llc(&hw[(size_t)(b0 + r) * NPAD + row], hp);  // write-through to LLC
    }

    // out block: must finish reading hr BEFORE publishing (WAR vs alm@t+3)
    if (is_outblk && t >= 1) {
      const uint32_t* hb = hr + (size_t)ob * NPAD + 1280 + ou0;
      float s = 0.f;
      #pragma unroll 10
      for (int i = 0; i < onu; ++i)
        s += unpack_h(hb[i]) * outw[ou0 + i];
      s += __shfl_xor(s, 1);
      s += __shfl_xor(s, 2);
      if (opart == 0)
        __builtin_nontemporal_store(s, &dout[OUT_OFF + ob * TSTEPS + (t - 1)]);
    }

    // drain: prior-step dout stores drained during this step; this waits only
    // the 8 fresh h stores (LLC ack) [+ out store for out blocks]
    asm volatile("s_waitcnt vmcnt(0)" ::: "memory");
    __builtin_amdgcn_s_barrier();            // all waves' h stores acked
    if (tid == 0)
      store_u32_llc(&cnt[ASLOT(g, nb)], (unsigned)(t + 1));   // publish h@t+1

    // ---- post-publish work (overlaps consumers' detect + own next poll) ----
    #pragma unroll
    for (int r = 0; r < 4; ++r) {
      if (valid) {
        int ei = ((b0 + r) * TSTEPS + t) * NREAL + row;
        __builtin_nontemporal_store(hvs[r], &dout[ei]);
        __builtin_nontemporal_store(xvs[r], &dout[XS_OFF + ei]);
      }
    }
    if (t + 1 < TSTEPS) {
      #pragma unroll
      for (int r = 0; r < 4; ++r) {
        if (valid) {
          int ei = ((b0 + r) * TSTEPS + (t + 1)) * NREAL + row;
          inh[r] = __builtin_nontemporal_load(&inhib[ei]);
          noi[r] = __builtin_nontemporal_load(&noise[ei]);
        }
      }
    }
  }

  // ---- out block: wait for alm@300, emit out[.][299] ----
  if (is_outblk) {
    if (poll_wave) {
      poll_wait(cnt, g, lane, in0, in1, false, false, (unsigned)TSTEPS, 0u);
      __builtin_amdgcn_fence(__ATOMIC_ACQUIRE, "agent");
      asm volatile("s_waitcnt vmcnt(0)" ::: "memory");
    }
    __builtin_amdgcn_s_barrier();
    asm volatile("" ::: "memory");
    const uint32_t* hr = hbuf + (size_t)(TSTEPS & 3) * P4;   // holds h@300
    const uint32_t* hb = hr + (size_t)ob * NPAD + 1280 + ou0;
    float s = 0.f;
    #pragma unroll 10
    for (int i = 0; i < onu; ++i)
      s += unpack_h(hb[i]) * outw[ou0 + i];
    s += __shfl_xor(s, 1);
    s += __shfl_xor(s, 2);
    if (opart == 0)
      __builtin_nontemporal_store(s, &dout[OUT_OFF + ob * TSTEPS + (TSTEPS - 1)]);
  }
}

// ---------------- host: numpy default_rng(0) sparse-mask reproduction ----------------
static void compute_sparse_mask(uint32_t* mb) {
  uint32_t pool[4];
  uint32_t hc = 0x43b0d7e5u;
  auto hashmix = [&hc](uint32_t value) -> uint32_t {
    value ^= hc; hc *= 0x931e8875u; value *= hc; value ^= value >> 16; return value;
  };
  // numpy bit_generator.pyx: mix(x,y) = (x*MIX_MULT_L - y*MIX_MULT_R) ^ >>16
  auto mixf = [](uint32_t x, uint32_t y) -> uint32_t {
    uint32_t r = x * 0xca01f9ddu;
    r -= y * 0x4973f715u;
    r ^= r >> 16;
    return r;
  };
  // SeedSequence(0): entropy=[0]
  for (int i = 0; i < 4; ++i) pool[i] = hashmix(0u);
  for (int s = 0; s < 4; ++s)
    for (int d = 0; d < 4; ++d)
      if (s != d) pool[d] = mixf(pool[d], hashmix(pool[s]));
  uint32_t st[8];
  uint32_t hb = 0x8b51f9ddu;
  for (int i = 0; i < 8; ++i) {
    uint32_t dv = pool[i & 3];
    dv ^= hb; hb *= 0x58f38dedu; dv *= hb; dv ^= dv >> 16;
    st[i] = dv;
  }
  uint64_t v64[4];
  for (int i = 0; i < 4; ++i) v64[i] = (uint64_t)st[2 * i] | ((uint64_t)st[2 * i + 1] << 32);
  typedef unsigned __int128 u128;
  const u128 MULT = ((u128)0x2360ed051fc65da4ULL << 64) | 0x4385df649fccf645ULL;
  u128 initstate = ((u128)v64[0] << 64) | v64[1];
  u128 initseq   = ((u128)v64[2] << 64) | v64[3];
  u128 state = 0, inc = (initseq << 1) | 1;
  state = state * MULT + inc;
  state += initstate;
  state = state * MULT + inc;
  bool has32 = false; uint32_t cached = 0;
  auto next64 = [&]() -> uint64_t {
    state = state * MULT + inc;
    uint64_t hi = (uint64_t)(state >> 64), lo = (uint64_t)state;
    unsigned rot = (unsigned)(state >> 122);
    uint64_t x = hi ^ lo;
    return (x >> rot) | (x << ((64 - rot) & 63));
  };
  auto next32 = [&]() -> uint32_t {
    if (has32) { has32 = false; return cached; }
    uint64_t v = next64();
    has32 = true; cached = (uint32_t)(v >> 32);
    return (uint32_t)v;
  };
  auto rinterval = [&](uint32_t mx) -> uint32_t {
    if (mx == 0) return 0;
    uint32_t mask = mx;
    mask |= mask >> 1; mask |= mask >> 2; mask |= mask >> 4;
    mask |= mask >> 8; mask |= mask >> 16;
    uint32_t value;
    do { value = next32() & mask; } while (value > mx);
    return value;
  };
  for (int i = 0; i < 256 * 8; ++i) mb[i] = 0xFFFFFFFFu;
  int perm[256];
  for (int c = 0; c < 256; ++c) {
    for (int i = 0; i < 256; ++i) perm[i] = i;
    for (int i = 255; i >= 1; --i) {
      uint32_t j = rinterval((uint32_t)i);
      int tmp = perm[i]; perm[i] = perm[j]; perm[j] = tmp;
    }
    for (int z = 0; z < 231; ++z)            // ceil(0.9*256)=231 zeros per column
      mb[perm[z] * 8 + (c >> 5)] &= ~(1u << (c & 31));
  }
}

// ---------------- launcher ----------------
extern "C" void kernel_launch(void* const* d_in, const int* in_sizes, int n_in,
                              void* d_out, int out_size, void* d_ws, size_t ws_size,
                              hipStream_t stream)
{
  (void)in_sizes; (void)n_in; (void)out_size; (void)ws_size;
  const float* inp   = (const float*)d_in[0];
  const float* cue   = (const float*)d_in[1];
  const float* inhib = (const float*)d_in[2];
  const float* hn    = (const float*)d_in[3];
  const float* xn    = (const float*)d_in[4];
  const float* noise = (const float*)d_in[5];
  const float* outw  = (const float*)d_in[21];
  float* dout = (float*)d_out;

  char* ws = (char*)d_ws;
  const size_t W_BYTES = (size_t)2 * NROWP * NPAD * sizeof(half_t);   // hi+lo planes
  const size_t H_BYTES = (size_t)4 * BATCH * NPAD * 4;                // ring-4 packed dword
  half_t*   W    = (half_t*)ws;
  uint32_t* hbuf = (uint32_t*)(ws + W_BYTES);
  unsigned int* mbits = (unsigned int*)(ws + W_BYTES + H_BYTES);
  unsigned int* cnt   = (unsigned int*)(ws + W_BYTES + H_BYTES + 32768);

  static uint32_t hmask[256 * 8];
  compute_sparse_mask(hmask);     // deterministic; host-side (capture-time only)
  (void)hipMemcpyAsync(mbits, hmask, sizeof(hmask), hipMemcpyHostToDevice, stream);
  (void)hipMemsetAsync(cnt, 0, 32768, stream);  // arrival slots zeroed per replay

  build_w<<<(NROWP * NPAD + 255) / 256, 256, 0, stream>>>(
      (const float*)d_in[6],  (const float*)d_in[7],  (const float*)d_in[8],
      (const float*)d_in[9],  (const float*)d_in[10], (const float*)d_in[11],
      (const float*)d_in[12], (const float*)d_in[13], (const float*)d_in[14],
      (const float*)d_in[15], (const float*)d_in[16], (const float*)d_in[17],
      (const float*)d_in[18], (const float*)d_in[19], (const float*)d_in[20],
      mbits, W);
  init_h<<<(BATCH * NPAD + 255) / 256, 256, 0, stream>>>(hn, hbuf);

  void* args[] = {(void*)&W, (void*)&hbuf, (void*)&cnt, (void*)&inp, (void*)&cue,
                  (void*)&inhib, (void*)&noise, (void*)&xn, (void*)&outw, (void*)&dout};
  hipError_t err = hipLaunchCooperativeKernel(reinterpret_cast<void*>(rnn_step_all),
                                              dim3(NGRP * NBLK), dim3(256), args, 0, stream);
  if (err != hipSuccess) {
    // fallback: plain launch (226 blocks <= 256 CUs -> co-resident in practice)
    rnn_step_all<<<dim3(NGRP * NBLK), dim3(256), 0, stream>>>(
        W, hbuf, cnt, inp, cue, inhib, noise, xn, outw, dout);
  }
}

// Round 16
// 3891.961 us; speedup vs baseline: 1.0379x; 1.0379x over previous
//
#include <hip/hip_runtime.h>
#include <stdint.h>
#include <string.h>

#define NREAL 1793
#define NPAD  1824          // K padded to 57*32
#define NROWP 1808          // rows padded to 113*16
#define WSTR  1832          // LDS row stride (halves)
#define NBLK  113
#define NGRP  2
#define TSTEPS 300
#define BATCH 128
#define XS_OFF 68851200     // 128*300*1793
#define OUT_OFF 137702400   // 2*128*300*1793
#define LOFF (16 * WSTR)    // LDS offset of lo-plane
#define LOSCALE 4096.0f
#define LOINV  2.44140625e-4f

// sync area: one arrival slot per block, each on its own 128B line
#define ASLOT(g,i)    (((g) * 128 + (i)) * 32)

typedef _Float16 half_t;
typedef __attribute__((ext_vector_type(8))) _Float16 half8;
typedef __attribute__((ext_vector_type(4))) float f32x4;
typedef __attribute__((ext_vector_type(4))) unsigned int uint4v;

__device__ __forceinline__ float clipw(float w) {
  return fminf(fmaxf(w, 1e-10f), 1.0f);
}

// write-through-to-LLC 4B store (bypasses L1/L2 -> agent-visible)
__device__ __forceinline__ void store_u32_llc(unsigned int* p, unsigned int v) {
  asm volatile("global_store_dword %0, %1, off sc0 sc1"
               :: "v"((unsigned long long)(uintptr_t)p), "v"(v)
               : "memory");
}

__device__ __forceinline__ float unpack_h(uint32_t p) {
  unsigned short uh = (unsigned short)(p & 0xffffu);
  unsigned short ul = (unsigned short)(p >> 16);
  half_t hh = *(half_t*)&uh;
  half_t hl = *(half_t*)&ul;
  return (float)hh + LOINV * (float)hl;
}

// tile-region id: 0 d1lo, 1 d1hi, 2 d2, 3 stn, 4 thal, 5 alm, 6 iti
__device__ __forceinline__ int rid_of(int s) {
  return (s < 8) ? 0 : (s < 16) ? 1 : (s < 32) ? 2 : (s < 48) ? 3
       : (s < 80) ? 4 : (s < 112) ? 5 : 6;
}

// masked dual-min poll over the 113 arrival slots (wave-wide)
__device__ __forceinline__ void poll_wait(unsigned int* cnt, int g, int lane,
                                          bool in0, bool in1, bool cn0, bool cn1,
                                          unsigned tin, unsigned tcn)
{
  const int s0 = lane, s1 = lane + 64;
  for (;;) {
    unsigned a0 = __hip_atomic_load(&cnt[ASLOT(g, s0)], __ATOMIC_RELAXED,
                                    __HIP_MEMORY_SCOPE_AGENT);
    unsigned a1 = 0xFFFFFFFFu;
    if (in1 || cn1)
      a1 = __hip_atomic_load(&cnt[ASLOT(g, s1)], __ATOMIC_RELAXED,
                             __HIP_MEMORY_SCOPE_AGENT);
    unsigned vin = in0 ? a0 : 0xFFFFFFFFu;
    if (in1 && a1 < vin) vin = a1;
    unsigned vcn = cn0 ? a0 : 0xFFFFFFFFu;
    if (cn1 && a1 < vcn) vcn = a1;
    #pragma unroll
    for (int o = 32; o; o >>= 1) {
      unsigned x = __shfl_xor(vin, o); if (x < vin) vin = x;
      unsigned y = __shfl_xor(vcn, o); if (y < vcn) vcn = y;
    }
    if (vin >= tin && vcn >= tcn) break;
    __builtin_amdgcn_s_sleep(1);
  }
}

// 2-deep software-pipelined burst: load batch j+1 while computing batch j.
// All indices compile-time (full unroll) -> registers, no scratch.
template<int LO0, int N0, int LO1, int N1, int LO2, int N2>
__device__ __forceinline__ void seg_mfma(const uint32_t* __restrict__ ap,
                                         const half_t* __restrict__ Wl, int wl_b,
                                         f32x4& acc0, f32x4& acc1, f32x4& acc2)
{
  constexpr int NC = N0 + N1 + N2;
  if constexpr (NC == 0) { return; }
  constexpr int BS = 8;
  constexpr int NB = (NC + BS - 1) / BS;
  uint4v qa0[BS], qa1[BS], qb0[BS], qb1[BS];

#define KC_OF(ci) ((ci) < N0 ? (LO0 + (ci)) : (ci) < N0 + N1 ? (LO1 + (ci) - N0) \
                              : (LO2 + (ci) - N0 - N1))

  // prologue: batch 0 -> a
  #pragma unroll
  for (int i = 0; i < BS; ++i) {
    if (i < NC) {
      const int kc = KC_OF(i);
      qa0[i] = *(const uint4v*)(ap + kc * 32);
      qa1[i] = *(const uint4v*)(ap + kc * 32 + 4);
    }
  }
  #pragma unroll
  for (int j = 0; j < NB; ++j) {
    // prefetch batch j+1 into the other buffer (issued before batch-j compute)
    if (j + 1 < NB) {
      #pragma unroll
      for (int i = 0; i < BS; ++i) {
        const int ci = (j + 1) * BS + i;
        if (ci < NC) {
          const int kc = KC_OF(ci);
          if (j % 2 == 0) {
            qb0[i] = *(const uint4v*)(ap + kc * 32);
            qb1[i] = *(const uint4v*)(ap + kc * 32 + 4);
          } else {
            qa0[i] = *(const uint4v*)(ap + kc * 32);
            qa1[i] = *(const uint4v*)(ap + kc * 32 + 4);
          }
        }
      }
    }
    // compute batch j
    #pragma unroll
    for (int i = 0; i < BS; ++i) {
      const int ci = j * BS + i;
      if (ci < NC) {
        const int kc = KC_OF(ci);
        uint4v v0 = (j % 2 == 0) ? qa0[i] : qb0[i];
        uint4v v1 = (j % 2 == 0) ? qa1[i] : qb1[i];
        uint4v uh, ul;
        uh.x = __builtin_amdgcn_perm(v0.y, v0.x, 0x05040100u);
        uh.y = __builtin_amdgcn_perm(v0.w, v0.z, 0x05040100u);
        uh.z = __builtin_amdgcn_perm(v1.y, v1.x, 0x05040100u);
        uh.w = __builtin_amdgcn_perm(v1.w, v1.z, 0x05040100u);
        ul.x = __builtin_amdgcn_perm(v0.y, v0.x, 0x07060302u);
        ul.y = __builtin_amdgcn_perm(v0.w, v0.z, 0x07060302u);
        ul.z = __builtin_amdgcn_perm(v1.y, v1.x, 0x07060302u);
        ul.w = __builtin_amdgcn_perm(v1.w, v1.z, 0x07060302u);
        union { uint4v u; half8 h; } ch, cl;
        ch.u = uh; cl.u = ul;
        half8 bvh = *(const half8*)&Wl[wl_b + kc * 32];
        half8 bvl = *(const half8*)&Wl[LOFF + wl_b + kc * 32];
        acc0 = __builtin_amdgcn_mfma_f32_16x16x32_f16(ch.h, bvh, acc0, 0, 0, 0);
        acc1 = __builtin_amdgcn_mfma_f32_16x16x32_f16(ch.h, bvl, acc1, 0, 0, 0);
        acc2 = __builtin_amdgcn_mfma_f32_16x16x32_f16(cl.h, bvh, acc2, 0, 0, 0);
      }
    }
  }
#undef KC_OF
}

// ---------------- W build (two fp16 planes: hi, lo*4096) ----------------
__global__ __launch_bounds__(256)
void build_w(const float* __restrict__ d12d1, const float* __restrict__ d12d2,
             const float* __restrict__ d22d1, const float* __restrict__ d22d2,
             const float* __restrict__ d22stn, const float* __restrict__ d12thal,
             const float* __restrict__ stn2thal, const float* __restrict__ thal2alm,
             const float* __restrict__ alm2alm, const float* __restrict__ thal2d1,
             const float* __restrict__ thal2d2, const float* __restrict__ alm2d1,
             const float* __restrict__ alm2d2, const float* __restrict__ inpw1,
             const float* __restrict__ inpw2, const unsigned int* __restrict__ mbits,
             half_t* __restrict__ W)
{
  int idx = blockIdx.x * 256 + threadIdx.x;
  if (idx >= NROWP * NPAD) return;
  int i = idx / NPAD, j = idx - (idx / NPAD) * NPAD;
  float v = 0.f;
  if (i < NREAL && j < NREAL) {
    if (i < 256) {
      if (j < 512) {
        int jj = j & 255;
        unsigned bit = (mbits[(i << 3) + (jj >> 5)] >> (jj & 31)) & 1u;
        float wv = (j < 256) ? d12d1[(i << 8) + jj] : d22d1[(i << 8) + jj];
        v = bit ? -clipw(wv) : 0.f;
      } else if (j < 768) {
      } else if (j < 1280) {
        if (i < 128) v = clipw(thal2d1[(i << 9) + (j - 768)]);
      } else if (j < 1792) {
        int jj = j - 1280;
        if (i >= 128 && jj < 359) v = clipw(alm2d1[(i << 9) + jj]);
      } else {
        if (i < 128) v = clipw(inpw1[i]);
      }
    } else if (i < 512) {
      int ii = i - 256;
      if (j < 512) {
        int jj = j & 255;
        unsigned bit = (mbits[(ii << 3) + (jj >> 5)] >> (jj & 31)) & 1u;
        float wv = (j < 256) ? d12d2[(ii << 8) + jj] : d22d2[(ii << 8) + jj];
        v = bit ? -clipw(wv) : 0.f;
      } else if (j < 768) {
      } else if (j < 1280) {
        v = clipw(thal2d2[(ii << 9) + (j - 768)]);
      } else if (j < 1792) {
        int jj = j - 1280;
        if (jj < 359) v = clipw(alm2d2[(ii << 9) + jj]);
      } else {
        v = clipw(inpw2[ii]);
      }
    } else if (i < 768) {
      int ii = i - 512;
      if (j >= 256 && j < 512) v = clipw(d22stn[(ii << 8) + (j - 256)]);
    } else if (i < 1280) {
      int ii = i - 768;
      if (j < 256) v = clipw(d12thal[(ii << 8) + j]);
      else if (j >= 512 && j < 768) v = -clipw(stn2thal[(ii << 8) + (j - 512)]);
    } else if (i < 1792) {
      int ii = i - 1280;
      if (j >= 768 && j < 1280) v = clipw(thal2alm[(ii << 9) + (j - 768)]);
      else if (j >= 1280) {
        int jj = j - 1280;
        v = clipw(alm2alm[(ii << 9) + jj]) * ((jj < 359) ? 1.f : -1.f);
      }
    }
  }
  half_t vh = (half_t)v;
  half_t vl = (half_t)((v - (float)vh) * LOSCALE);
  W[idx] = vh;                                  // hi plane
  W[(size_t)NROWP * NPAD + idx] = vl;           // lo plane (scaled)
}

// ---------------- h0 init (packed dword per unit; ring buffer 0) ----------------
__global__ __launch_bounds__(256)
void init_h(const float* __restrict__ hn, uint32_t* __restrict__ hbuf)
{
  const size_t P4 = (size_t)BATCH * NPAD;
  int idx = blockIdx.x * 256 + threadIdx.x;
  if (idx >= BATCH * NPAD) return;
  int b = idx / NPAD, k = idx - b * NPAD;
  float v = (k < NREAL) ? hn[b * NREAL + k] : 0.f;
  half_t vh = (half_t)v;
  half_t vl = (half_t)((v - (float)vh) * LOSCALE);
  uint32_t hp = (uint32_t)(*(unsigned short*)&vh) |
                ((uint32_t)(*(unsigned short*)&vl) << 16);
  hbuf[idx]      = hp;   // ring buf 0 = h@0
  hbuf[P4 + idx] = 0u;   // ring buf 1 cleared (2,3 are W-zero-protected)
}

// ---------------- main cooperative RNN kernel (226 blocks x 4 waves) ----------------
__global__ __launch_bounds__(256, 1)
void rnn_step_all(const half_t* __restrict__ Wg, uint32_t* __restrict__ hbuf,
                  unsigned int* __restrict__ cnt,
                  const float* __restrict__ inp, const float* __restrict__ cue,
                  const float* __restrict__ inhib, const float* __restrict__ noise,
                  const float* __restrict__ xn, const float* __restrict__ outw,
                  float* __restrict__ dout)
{
  __shared__ __align__(16) half_t Wl[2 * 16 * WSTR];   // 117 KB: hi + lo planes
  const int tid = threadIdx.x;
  const int bid = blockIdx.x;
  const int g  = bid / NBLK;
  const int nb = bid - g * NBLK;
  const int r0 = nb * 16;
  const int bg = g * 64;
  const size_t P4 = (size_t)BATCH * NPAD;

  const int lane = tid & 63;
  const int w    = tid >> 6;      // wave = M-tile (16 batch rows)
  const int n_i  = lane & 15;     // output unit within tile
  const int kq   = lane >> 4;     // k-subgroup
  const int row  = r0 + n_i;      // global unit index
  const bool valid = row < NREAL;
  const int b0 = bg + 16 * w + kq * 4;   // batch base for the 4 acc regs
  const int bA = bg + 16 * w + n_i;      // batch row this lane loads for A-frag
  const int wl_b = n_i * WSTR + kq * 8;
  const bool is_outblk = (r0 == 512);    // one near-idle stn block per group
  const bool poll_wave = (tid < 64);

  // ---- dataflow masks ----
  const int myrid = rid_of(nb);
  const unsigned INB =
      (myrid == 0) ? 87u : (myrid == 1) ? 39u : (myrid == 2) ? 119u :
      (myrid == 3) ? ((nb == 32) ? 36u : 4u) :
      (myrid == 4) ? 11u : (myrid == 5) ? 48u : 0u;
  const unsigned CONSB =
      (myrid <= 1) ? 23u : (myrid == 2) ? 15u : (myrid == 3) ? 16u :
      (myrid == 4) ? 37u : (myrid == 5) ? 46u : 5u;
  const int s1 = lane + 64;
  const int rid0 = rid_of(lane);
  const int rid1 = (s1 < NBLK) ? rid_of(s1) : 6;
  const bool in0 = (lane != nb) && ((INB >> rid0) & 1);
  const bool in1 = (s1 < NBLK) && (s1 != nb) && ((INB >> rid1) & 1);
  const bool cn0 = ((CONSB >> rid0) & 1);
  const bool cn1 = (s1 < NBLK) && ((CONSB >> rid1) & 1);

  // preload t=0 streams (overlaps W staging)
  float inh[4], noi[4];
  #pragma unroll
  for (int r = 0; r < 4; ++r) {
    inh[r] = 0.f; noi[r] = 0.f;
    if (valid) {
      int ei = ((b0 + r) * TSTEPS) * NREAL + row;
      inh[r] = __builtin_nontemporal_load(&inhib[ei]);
      noi[r] = __builtin_nontemporal_load(&noise[ei]);
    }
  }

  // stage this block's 16 W rows, both planes, into LDS (reused for 300 steps)
  for (int idx = tid; idx < 2 * 16 * (NPAD / 8); idx += 256) {
    int p   = idx / (16 * (NPAD / 8));
    int rem = idx - p * 16 * (NPAD / 8);
    int rr  = rem / (NPAD / 8);
    int cc  = (rem - rr * (NPAD / 8)) * 8;
    *(uint4v*)&Wl[p * LOFF + rr * WSTR + cc] =
        *(const uint4v*)&Wg[(size_t)p * NROWP * NPAD + (size_t)(r0 + rr) * NPAD + cc];
  }
  __syncthreads();

  float xr[4];
  #pragma unroll
  for (int r = 0; r < 4; ++r)
    xr[r] = valid ? xn[(size_t)(b0 + r) * NREAL + row] : 0.f;

  const float tonic = (valid && row < 1792) ? 0.1f : 0.f;
  const bool is_iti = (row == 1792);

  // out-compute lane mapping (used only by out blocks)
  const int ob    = bg + 16 * w + (lane >> 2);   // batch this lane helps with
  const int opart = lane & 3;
  const int ou0   = opart * 90;
  const int onu   = (opart == 3) ? 89 : 90;

  #pragma unroll 1
  for (int t = 0; t < TSTEPS; ++t) {
    // ---- dataflow wait: inputs@t available, consumers consumed h@t-3 ----
    if (t >= 1) {
      if (poll_wave) {
        poll_wait(cnt, g, lane, in0, in1, cn0, cn1,
                  (unsigned)t, (t >= 2) ? (unsigned)(t - 2) : 0u);
        __builtin_amdgcn_fence(__ATOMIC_ACQUIRE, "agent");   // L1+L2 inv
        asm volatile("s_waitcnt vmcnt(0)" ::: "memory");
      }
      __builtin_amdgcn_s_barrier();
      asm volatile("" ::: "memory");
    }

    const uint32_t* hr = hbuf + (size_t)(t & 3) * P4;        // h@t (ring)
    uint32_t*       hw = hbuf + (size_t)((t + 1) & 3) * P4;  // h@t+1

    float itv[4];
    #pragma unroll
    for (int r = 0; r < 4; ++r) {
      int bt = (b0 + r) * TSTEPS + t;
      itv[r] = is_iti ? (inp[bt] + cue[bt]) : 0.f;
    }

    const uint32_t* ap = hr + (size_t)bA * NPAD + kq * 8;
    f32x4 acc0 = {0.f, 0.f, 0.f, 0.f};
    f32x4 acc1 = {0.f, 0.f, 0.f, 0.f};
    f32x4 acc2 = {0.f, 0.f, 0.f, 0.f};

    if      (r0 < 128)  seg_mfma<0, 16, 24, 16, 56, 1>(ap, Wl, wl_b, acc0, acc1, acc2);
    else if (r0 < 256)  seg_mfma<0, 16, 40, 12,  0, 0>(ap, Wl, wl_b, acc0, acc1, acc2);
    else if (r0 < 512)  seg_mfma<0, 16, 24, 28, 56, 1>(ap, Wl, wl_b, acc0, acc1, acc2);
    else if (r0 < 768)  seg_mfma<8,  8,  0,  0,  0, 0>(ap, Wl, wl_b, acc0, acc1, acc2);
    else if (r0 < 1280) seg_mfma<0,  8, 16,  8,  0, 0>(ap, Wl, wl_b, acc0, acc1, acc2);
    else if (r0 < 1792) seg_mfma<24, 32, 0,  0,  0, 0>(ap, Wl, wl_b, acc0, acc1, acc2);
    // r0 == 1792: zero W rows, acc stays 0

    #pragma unroll
    for (int r = 0; r < 4; ++r) {
      float drive = acc0[r] + LOINV * (acc1[r] + acc2[r])
                    + tonic + inh[r] + 0.01f * noi[r] + itv[r];
      float xv = xr[r] + 0.1f * (drive - xr[r]);     // matches ref: x + dt*(-x+drive)
      float hv = fmaxf(xv, 0.f);
      xr[r] = xv;
      int bt = (b0 + r) * TSTEPS + t;
      if (valid) {
        int ei = bt * NREAL + row;
        __builtin_nontemporal_store(hv, &dout[ei]);
        __builtin_nontemporal_store(xv, &dout[XS_OFF + ei]);
      }
      half_t hh = (half_t)hv;
      half_t hl = (half_t)((hv - (float)hh) * LOSCALE);
      uint32_t hp = (uint32_t)(*(unsigned short*)&hh) |
                    ((uint32_t)(*(unsigned short*)&hl) << 16);
      store_u32_llc(&hw[(size_t)(b0 + r) * NPAD + row], hp);  // write-through to LLC
    }

    // designated out block: compute out[.][t-1] from hr (h@t), no atomics
    if (is_outblk && t >= 1) {
      const uint32_t* hb = hr + (size_t)ob * NPAD + 1280 + ou0;
      float s = 0.f;
      #pragma unroll 10
      for (int i = 0; i < onu; ++i)
        s += unpack_h(hb[i]) * outw[ou0 + i];
      s += __shfl_xor(s, 1);
      s += __shfl_xor(s, 2);
      if (opart == 0)
        __builtin_nontemporal_store(s, &dout[OUT_OFF + ob * TSTEPS + (t - 1)]);
    }

    // prefetch next step's streams (stay in flight across the publish)
    if (t + 1 < TSTEPS) {
      #pragma unroll
      for (int r = 0; r < 4; ++r) {
        if (valid) {
          int ei = ((b0 + r) * TSTEPS + (t + 1)) * NREAL + row;
          inh[r] = __builtin_nontemporal_load(&inhib[ei]);
          noi[r] = __builtin_nontemporal_load(&noise[ei]);
        }
      }
      // counted drain: last 8 VMEM ops are the prefetch loads -> h stores acked
      asm volatile("s_waitcnt vmcnt(8)" ::: "memory");
    } else {
      asm volatile("s_waitcnt vmcnt(0)" ::: "memory");
    }
    __builtin_amdgcn_s_barrier();            // all waves' h stores drained
    if (tid == 0)
      store_u32_llc(&cnt[ASLOT(g, nb)], (unsigned)(t + 1));   // publish h@t+1
  }

  // ---- out block: wait for alm@300, emit out[.][299] ----
  if (is_outblk) {
    if (poll_wave) {
      poll_wait(cnt, g, lane, in0, in1, false, false, (unsigned)TSTEPS, 0u);
      __builtin_amdgcn_fence(__ATOMIC_ACQUIRE, "agent");
      asm volatile("s_waitcnt vmcnt(0)" ::: "memory");
    }
    __builtin_amdgcn_s_barrier();
    asm volatile("" ::: "memory");
    const uint32_t* hr = hbuf + (size_t)(TSTEPS & 3) * P4;   // holds h@300
    const uint32_t* hb = hr + (size_t)ob * NPAD + 1280 + ou0;
    float s = 0.f;
    #pragma unroll 10
    for (int i = 0; i < onu; ++i)
      s += unpack_h(hb[i]) * outw[ou0 + i];
    s += __shfl_xor(s, 1);
    s += __shfl_xor(s, 2);
    if (opart == 0)
      __builtin_nontemporal_store(s, &dout[OUT_OFF + ob * TSTEPS + (TSTEPS - 1)]);
  }
}

// ---------------- host: numpy default_rng(0) sparse-mask reproduction ----------------
static void compute_sparse_mask(uint32_t* mb) {
  uint32_t pool[4];
  uint32_t hc = 0x43b0d7e5u;
  auto hashmix = [&hc](uint32_t value) -> uint32_t {
    value ^= hc; hc *= 0x931e8875u; value *= hc; value ^= value >> 16; return value;
  };
  // numpy bit_generator.pyx: mix(x,y) = (x*MIX_MULT_L - y*MIX_MULT_R) ^ >>16
  auto mixf = [](uint32_t x, uint32_t y) -> uint32_t {
    uint32_t r = x * 0xca01f9ddu;
    r -= y * 0x4973f715u;
    r ^= r >> 16;
    return r;
  };
  // SeedSequence(0): entropy=[0]
  for (int i = 0; i < 4; ++i) pool[i] = hashmix(0u);
  for (int s = 0; s < 4; ++s)
    for (int d = 0; d < 4; ++d)
      if (s != d) pool[d] = mixf(pool[d], hashmix(pool[s]));
  uint32_t st[8];
  uint32_t hb = 0x8b51f9ddu;
  for (int i = 0; i < 8; ++i) {
    uint32_t dv = pool[i & 3];
    dv ^= hb; hb *= 0x58f38dedu; dv *= hb; dv ^= dv >> 16;
    st[i] = dv;
  }
  uint64_t v64[4];
  for (int i = 0; i < 4; ++i) v64[i] = (uint64_t)st[2 * i] | ((uint64_t)st[2 * i + 1] << 32);
  typedef unsigned __int128 u128;
  const u128 MULT = ((u128)0x2360ed051fc65da4ULL << 64) | 0x4385df649fccf645ULL;
  u128 initstate = ((u128)v64[0] << 64) | v64[1];
  u128 initseq   = ((u128)v64[2] << 64) | v64[3];
  u128 state = 0, inc = (initseq << 1) | 1;
  state = state * MULT + inc;
  state += initstate;
  state = state * MULT + inc;
  bool has32 = false; uint32_t cached = 0;
  auto next64 = [&]() -> uint64_t {
    state = state * MULT + inc;
    uint64_t hi = (uint64_t)(state >> 64), lo = (uint64_t)state;
    unsigned rot = (unsigned)(state >> 122);
    uint64_t x = hi ^ lo;
    return (x >> rot) | (x << ((64 - rot) & 63));
  };
  auto next32 = [&]() -> uint32_t {
    if (has32) { has32 = false; return cached; }
    uint64_t v = next64();
    has32 = true; cached = (uint32_t)(v >> 32);
    return (uint32_t)v;
  };
  auto rinterval = [&](uint32_t mx) -> uint32_t {
    if (mx == 0) return 0;
    uint32_t mask = mx;
    mask |= mask >> 1; mask |= mask >> 2; mask |= mask >> 4;
    mask |= mask >> 8; mask |= mask >> 16;
    uint32_t value;
    do { value = next32() & mask; } while (value > mx);
    return value;
  };
  for (int i = 0; i < 256 * 8; ++i) mb[i] = 0xFFFFFFFFu;
  int perm[256];
  for (int c = 0; c < 256; ++c) {
    for (int i = 0; i < 256; ++i) perm[i] = i;
    for (int i = 255; i >= 1; --i) {
      uint32_t j = rinterval((uint32_t)i);
      int tmp = perm[i]; perm[i] = perm[j]; perm[j] = tmp;
    }
    for (int z = 0; z < 231; ++z)            // ceil(0.9*256)=231 zeros per column
      mb[perm[z] * 8 + (c >> 5)] &= ~(1u << (c & 31));
  }
}

// ---------------- launcher ----------------
extern "C" void kernel_launch(void* const* d_in, const int* in_sizes, int n_in,
                              void* d_out, int out_size, void* d_ws, size_t ws_size,
                              hipStream_t stream)
{
  (void)in_sizes; (void)n_in; (void)out_size; (void)ws_size;
  const float* inp   = (const float*)d_in[0];
  const float* cue   = (const float*)d_in[1];
  const float* inhib = (const float*)d_in[2];
  const float* hn    = (const float*)d_in[3];
  const float* xn    = (const float*)d_in[4];
  const float* noise = (const float*)d_in[5];
  const float* outw  = (const float*)d_in[21];
  float* dout = (float*)d_out;

  char* ws = (char*)d_ws;
  const size_t W_BYTES = (size_t)2 * NROWP * NPAD * sizeof(half_t);   // hi+lo planes
  const size_t H_BYTES = (size_t)4 * BATCH * NPAD * 4;                // ring-4 packed dword
  half_t*   W    = (half_t*)ws;
  uint32_t* hbuf = (uint32_t*)(ws + W_BYTES);
  unsigned int* mbits = (unsigned int*)(ws + W_BYTES + H_BYTES);
  unsigned int* cnt   = (unsigned int*)(ws + W_BYTES + H_BYTES + 32768);

  static uint32_t hmask[256 * 8];
  compute_sparse_mask(hmask);     // deterministic; host-side (capture-time only)
  (void)hipMemcpyAsync(mbits, hmask, sizeof(hmask), hipMemcpyHostToDevice, stream);
  (void)hipMemsetAsync(cnt, 0, 32768, stream);  // arrival slots zeroed per replay

  build_w<<<(NROWP * NPAD + 255) / 256, 256, 0, stream>>>(
      (const float*)d_in[6],  (const float*)d_in[7],  (const float*)d_in[8],
      (const float*)d_in[9],  (const float*)d_in[10], (const float*)d_in[11],
      (const float*)d_in[12], (const float*)d_in[13], (const float*)d_in[14],
      (const float*)d_in[15], (const float*)d_in[16], (const float*)d_in[17],
      (const float*)d_in[18], (const float*)d_in[19], (const float*)d_in[20],
      mbits, W);
  init_h<<<(BATCH * NPAD + 255) / 256, 256, 0, stream>>>(hn, hbuf);

  void* args[] = {(void*)&W, (void*)&hbuf, (void*)&cnt, (void*)&inp, (void*)&cue,
                  (void*)&inhib, (void*)&noise, (void*)&xn, (void*)&outw, (void*)&dout};
  hipError_t err = hipLaunchCooperativeKernel(reinterpret_cast<void*>(rnn_step_all),
                                              dim3(NGRP * NBLK), dim3(256), args, 0, stream);
  if (err != hipSuccess) {
    // fallback: plain launch (226 blocks <= 256 CUs -> co-resident in practice)
    rnn_step_all<<<dim3(NGRP * NBLK), dim3(256), 0, stream>>>(
        W, hbuf, cnt, inp, cue, inhib, noise, xn, outw, dout);
  }
}